// Round 7
// baseline (254.431 us; speedup 1.0000x reference)
//
#include <hip/hip_runtime.h>

#define NPOS 4096
#define CDIM 256
#define FDIM 64

typedef short short8 __attribute__((ext_vector_type(8)));
typedef float f32x4 __attribute__((ext_vector_type(4)));

__device__ __forceinline__ unsigned short f2bf(float v) {
  unsigned u = __float_as_uint(v);
  unsigned r = (u + 0x7fffu + ((u >> 16) & 1u)) >> 16;  // RNE
  return (unsigned short)r;
}
__device__ __forceinline__ float bf2f(unsigned short u) {
  return __uint_as_float((unsigned)u << 16);
}
__device__ __forceinline__ short8 as_s8(uint4 u) {
  return *reinterpret_cast<short8*>(&u);
}

// ---------------------------------------------------------------------------
// Kernel 1: projections.
//   f,g emitted as bf16 hi/lo split planes [8192][64] (for bf16x3 MFMA s)
//   h_t = (x@Wh)^T in bf16: [b][col 256][row 4096]
// ---------------------------------------------------------------------------
__global__ __launch_bounds__(256) void proj_kernel(
    const float* __restrict__ x, const float* __restrict__ Wf,
    const float* __restrict__ Wg, const float* __restrict__ Wh,
    unsigned short* __restrict__ f_hi, unsigned short* __restrict__ f_lo,
    unsigned short* __restrict__ g_hi, unsigned short* __restrict__ g_lo,
    unsigned short* __restrict__ h_t) {
  __shared__ float xs[16][CDIM];
  const int row0 = blockIdx.x * 16;
  const int t = threadIdx.x;
  {
    const float4* xv = reinterpret_cast<const float4*>(x + (size_t)row0 * CDIM);
    float4* sv = reinterpret_cast<float4*>(&xs[0][0]);
#pragma unroll
    for (int i = 0; i < 4; ++i) sv[t + 256 * i] = xv[t + 256 * i];
  }
  __syncthreads();
  // h projection -> h_t bf16 (thread t owns output column t, 16 rows)
  {
    float acc[16];
#pragma unroll
    for (int r = 0; r < 16; ++r) acc[r] = 0.f;
    for (int k = 0; k < CDIM; k += 4) {
      const float w0 = Wh[(size_t)(k + 0) * CDIM + t];
      const float w1 = Wh[(size_t)(k + 1) * CDIM + t];
      const float w2 = Wh[(size_t)(k + 2) * CDIM + t];
      const float w3 = Wh[(size_t)(k + 3) * CDIM + t];
#pragma unroll
      for (int r = 0; r < 16; ++r) {
        const float4 xv = *reinterpret_cast<const float4*>(&xs[r][k]);
        float a = acc[r];
        a = fmaf(xv.x, w0, a);
        a = fmaf(xv.y, w1, a);
        a = fmaf(xv.z, w2, a);
        a = fmaf(xv.w, w3, a);
        acc[r] = a;
      }
    }
    const int b = row0 >> 12;
    const int lr = row0 & (NPOS - 1);
    unsigned wd[8];
#pragma unroll
    for (int i = 0; i < 8; ++i)
      wd[i] = (unsigned)f2bf(acc[2 * i]) | ((unsigned)f2bf(acc[2 * i + 1]) << 16);
    uint4* dst = reinterpret_cast<uint4*>(h_t + ((size_t)(b * CDIM + t)) * NPOS + lr);
    dst[0] = make_uint4(wd[0], wd[1], wd[2], wd[3]);
    dst[1] = make_uint4(wd[4], wd[5], wd[6], wd[7]);
  }
  // f,g projections with hi/lo bf16 split
  {
    const int col = t & 63;
    const int rb = (t >> 6) * 4;
    float af[4] = {0.f, 0.f, 0.f, 0.f};
    float ag[4] = {0.f, 0.f, 0.f, 0.f};
    for (int k = 0; k < CDIM; k += 4) {
      const float wf0 = Wf[(size_t)(k + 0) * FDIM + col];
      const float wf1 = Wf[(size_t)(k + 1) * FDIM + col];
      const float wf2 = Wf[(size_t)(k + 2) * FDIM + col];
      const float wf3 = Wf[(size_t)(k + 3) * FDIM + col];
      const float wg0 = Wg[(size_t)(k + 0) * FDIM + col];
      const float wg1 = Wg[(size_t)(k + 1) * FDIM + col];
      const float wg2 = Wg[(size_t)(k + 2) * FDIM + col];
      const float wg3 = Wg[(size_t)(k + 3) * FDIM + col];
#pragma unroll
      for (int r = 0; r < 4; ++r) {
        const float4 xv = *reinterpret_cast<const float4*>(&xs[rb + r][k]);
        float a = af[r], bb = ag[r];
        a = fmaf(xv.x, wf0, a); a = fmaf(xv.y, wf1, a);
        a = fmaf(xv.z, wf2, a); a = fmaf(xv.w, wf3, a);
        bb = fmaf(xv.x, wg0, bb); bb = fmaf(xv.y, wg1, bb);
        bb = fmaf(xv.z, wg2, bb); bb = fmaf(xv.w, wg3, bb);
        af[r] = a; ag[r] = bb;
      }
    }
#pragma unroll
    for (int r = 0; r < 4; ++r) {
      const size_t o = (size_t)(row0 + rb + r) * FDIM + col;
      const unsigned short fh = f2bf(af[r]);
      const unsigned short gh = f2bf(ag[r]);
      f_hi[o] = fh;
      f_lo[o] = f2bf(af[r] - bf2f(fh));
      g_hi[o] = gh;
      g_lo[o] = f2bf(ag[r] - bf2f(gh));
    }
  }
}

// ---------------------------------------------------------------------------
// Kernel 2 (FUSED): per block = 16 beta-rows.
//  Phase A: s = g f^T via bf16x3 MFMA with SWAPPED operands (A=f, B=g) so each
//    lane holds 4 consecutive k of one beta-row; exp fp32 -> bf16 -> LDS plane
//    P (16 x 4096, 128 KiB, 16B-chunk XOR swizzle). Accumulate l. s never
//    touches HBM (saves 268 MB vs the 3-kernel pipeline).
//  Phase B: beta = exp * (1/l) written once (only large HBM term), then
//    o = P @ h_t with 8-deep named-register load pipeline pinned by
//    sched_barrier(0) (r5/r6 lesson: unpinned "batches" get re-serialized).
//  out = gamma * o / l + x.
// ---------------------------------------------------------------------------
__global__ __launch_bounds__(512, 2) void attn_fused_kernel(
    const unsigned short* __restrict__ f_hi, const unsigned short* __restrict__ f_lo,
    const unsigned short* __restrict__ g_hi, const unsigned short* __restrict__ g_lo,
    const unsigned short* __restrict__ h_t, const float* __restrict__ x,
    const float* __restrict__ gamma, float* __restrict__ beta,
    float* __restrict__ out) {
  __shared__ uint2 P2[16][1024];   // exp(s) bf16: row r, 512 swizzled 16B chunks
  __shared__ float partl[8][16];
  __shared__ float linv[16];

  const int wg = blockIdx.x;
  const int wgid = (wg & 7) * 64 + (wg >> 3);   // bijective XCD chunking (512 wgs)
  const int b = wgid >> 8;
  const int row0 = (wgid & 255) * 16;
  const int t = threadIdx.x;
  const int w = t >> 6;
  const int l = t & 63;
  const int lr = l & 15;
  const int lk = l >> 4;
  const int swz = lr & 7;

  // ---- g fragments (MFMA B-operand): beta-rows row0..row0+15
  short8 gh[2], gl[2];
  {
    const unsigned short* gH = g_hi + ((size_t)(b * NPOS + row0 + lr)) * FDIM + lk * 8;
    const unsigned short* gL = g_lo + ((size_t)(b * NPOS + row0 + lr)) * FDIM + lk * 8;
    gh[0] = *reinterpret_cast<const short8*>(gH);
    gh[1] = *reinterpret_cast<const short8*>(gH + 32);
    gl[0] = *reinterpret_cast<const short8*>(gL);
    gl[1] = *reinterpret_cast<const short8*>(gL + 32);
  }

  // ============================ Phase A ============================
  const unsigned short* fh = f_hi + (size_t)b * NPOS * FDIM + (size_t)lr * FDIM + lk * 8;
  const unsigned short* fl = f_lo + (size_t)b * NPOS * FDIM + (size_t)lr * FDIM + lk * 8;
  const int colbase = w * 512;   // wave's 512-col strip
  float lsum = 0.f;

  uint4 Ah0, Ah1, Al0, Al1, Bh0, Bh1, Bl0, Bl1;

#define LOADF(G, ct)                                                          \
  do {                                                                        \
    const size_t off_ = (size_t)(colbase + (ct) * 16) * FDIM;                 \
    G##h0 = *reinterpret_cast<const uint4*>(fh + off_);                       \
    G##h1 = *reinterpret_cast<const uint4*>(fh + off_ + 32);                  \
    G##l0 = *reinterpret_cast<const uint4*>(fl + off_);                       \
    G##l1 = *reinterpret_cast<const uint4*>(fl + off_ + 32);                  \
  } while (0)

#define TILEA(G, ct)                                                          \
  do {                                                                        \
    f32x4 acca = {0.f, 0.f, 0.f, 0.f}, accb = {0.f, 0.f, 0.f, 0.f};           \
    acca = __builtin_amdgcn_mfma_f32_16x16x32_bf16(as_s8(G##h0), gh[0], acca, 0, 0, 0); \
    accb = __builtin_amdgcn_mfma_f32_16x16x32_bf16(as_s8(G##l0), gh[0], accb, 0, 0, 0); \
    acca = __builtin_amdgcn_mfma_f32_16x16x32_bf16(as_s8(G##h0), gl[0], acca, 0, 0, 0); \
    accb = __builtin_amdgcn_mfma_f32_16x16x32_bf16(as_s8(G##h1), gh[1], accb, 0, 0, 0); \
    acca = __builtin_amdgcn_mfma_f32_16x16x32_bf16(as_s8(G##l1), gh[1], acca, 0, 0, 0); \
    accb = __builtin_amdgcn_mfma_f32_16x16x32_bf16(as_s8(G##h1), gl[1], accb, 0, 0, 0); \
    const f32x4 av = acca + accb;                                             \
    const float e0 = __expf(av[0]), e1 = __expf(av[1]);                       \
    const float e2 = __expf(av[2]), e3 = __expf(av[3]);                       \
    lsum += (e0 + e1) + (e2 + e3);                                            \
    uint2 pk_;                                                                \
    pk_.x = (unsigned)f2bf(e0) | ((unsigned)f2bf(e1) << 16);                  \
    pk_.y = (unsigned)f2bf(e2) | ((unsigned)f2bf(e3) << 16);                  \
    const int kb_ = colbase + (ct) * 16 + lk * 4;                             \
    P2[lr][(((kb_ >> 3) ^ swz) << 1) | (lk & 1)] = pk_;                       \
  } while (0)

  LOADF(A, 0);
  LOADF(B, 1);
  for (int ct = 0; ct < 32; ct += 2) {
    TILEA(A, ct);
    if (ct + 2 < 32) LOADF(A, ct + 2);
    __builtin_amdgcn_sched_barrier(0);
    TILEA(B, ct + 1);
    if (ct + 3 < 32) LOADF(B, ct + 3);
    __builtin_amdgcn_sched_barrier(0);
  }
#undef LOADF
#undef TILEA

  // per-row l: lanes {l, l^16, l^32, l^48} share beta-row lr
  lsum += __shfl_xor(lsum, 16);
  lsum += __shfl_xor(lsum, 32);
  if (l < 16) partl[w][l] = lsum;
  __syncthreads();
  if (t < 16) {
    float s = 0.f;
#pragma unroll
    for (int q = 0; q < 8; ++q) s += partl[q][t];
    linv[t] = __frcp_rn(s);
  }
  __syncthreads();

  // ============================ beta write ============================
  float* betab = beta + (size_t)b * NPOS * NPOS;
  {
    const int rb = t >> 5;            // beta-row 0..15
    const int j0 = (t & 31) * 4;      // k phase
    const float ilr = linv[rb];
    const int rsw = rb & 7;
    float* brow = betab + (size_t)(row0 + rb) * NPOS;
    const uint2* prow = &P2[rb][0];
#pragma unroll 4
    for (int j = 0; j < 32; ++j) {
      const int k = j0 + j * 128;
      const uint2 pk = prow[(((k >> 3) ^ rsw) << 1) | ((k >> 2) & 1)];
      float4 v;
      v.x = bf2f((unsigned short)(pk.x & 0xffffu)) * ilr;
      v.y = bf2f((unsigned short)(pk.x >> 16)) * ilr;
      v.z = bf2f((unsigned short)(pk.y & 0xffffu)) * ilr;
      v.w = bf2f((unsigned short)(pk.y >> 16)) * ilr;
      *reinterpret_cast<float4*>(brow + k) = v;
    }
  }

  // ============================ Phase B: PV ============================
  const int wcol = w * 32;
  const unsigned short* hb =
      h_t + (size_t)b * CDIM * NPOS + (size_t)(wcol + lr) * NPOS + lk * 8;
  const uint4* Pv4 = reinterpret_cast<const uint4*>(&P2[lr][0]);
  f32x4 acc0 = {0.f, 0.f, 0.f, 0.f}, acc1 = {0.f, 0.f, 0.f, 0.f};

  uint4 G0a, G0b0, G0b1, G1a, G1b0, G1b1, G2a, G2b0, G2b1, G3a, G3b0, G3b1;
  uint4 G4a, G4b0, G4b1, G5a, G5b0, G5b1, G6a, G6b0, G6b1, G7a, G7b0, G7b1;

#define LOADPV(G, k)                                                          \
  do {                                                                        \
    G##a = Pv4[(((k) >> 3) + lk) ^ swz];                                      \
    G##b0 = *reinterpret_cast<const uint4*>(hb + (k));                        \
    G##b1 = *reinterpret_cast<const uint4*>(hb + (k) + 16 * NPOS);            \
  } while (0)

#define PVM(G)                                                                \
  do {                                                                        \
    const short8 afr_ = as_s8(G##a);                                          \
    acc0 = __builtin_amdgcn_mfma_f32_16x16x32_bf16(afr_, as_s8(G##b0), acc0, 0, 0, 0); \
    acc1 = __builtin_amdgcn_mfma_f32_16x16x32_bf16(afr_, as_s8(G##b1), acc1, 0, 0, 0); \
  } while (0)

  LOADPV(G0, 0);   LOADPV(G1, 32);  LOADPV(G2, 64);  LOADPV(G3, 96);
  LOADPV(G4, 128); LOADPV(G5, 160); LOADPV(G6, 192); LOADPV(G7, 224);
  for (int k0 = 0; k0 < NPOS; k0 += 256) {
    const bool pf = (k0 + 256) < NPOS;
    PVM(G0); if (pf) LOADPV(G0, k0 + 256); __builtin_amdgcn_sched_barrier(0);
    PVM(G1); if (pf) LOADPV(G1, k0 + 288); __builtin_amdgcn_sched_barrier(0);
    PVM(G2); if (pf) LOADPV(G2, k0 + 320); __builtin_amdgcn_sched_barrier(0);
    PVM(G3); if (pf) LOADPV(G3, k0 + 352); __builtin_amdgcn_sched_barrier(0);
    PVM(G4); if (pf) LOADPV(G4, k0 + 384); __builtin_amdgcn_sched_barrier(0);
    PVM(G5); if (pf) LOADPV(G5, k0 + 416); __builtin_amdgcn_sched_barrier(0);
    PVM(G6); if (pf) LOADPV(G6, k0 + 448); __builtin_amdgcn_sched_barrier(0);
    PVM(G7); if (pf) LOADPV(G7, k0 + 480); __builtin_amdgcn_sched_barrier(0);
  }
#undef LOADPV
#undef PVM

  // epilogue: out = gamma*o/l + x ; C/D: col=lane&15, row=(lane>>4)*4+reg
  const float gam = gamma[0];
#pragma unroll
  for (int r = 0; r < 4; ++r) {
    const int orow = row0 + lk * 4 + r;
    const float sc = gam * linv[lk * 4 + r];
    const size_t i0 = ((size_t)b * NPOS + orow) * CDIM + wcol + lr;
    out[i0] = fmaf(sc, acc0[r], x[i0]);
    out[i0 + 16] = fmaf(sc, acc1[r], x[i0 + 16]);
  }
}

extern "C" void kernel_launch(void* const* d_in, const int* in_sizes, int n_in,
                              void* d_out, int out_size, void* d_ws, size_t ws_size,
                              hipStream_t stream) {
  (void)in_sizes; (void)n_in; (void)out_size; (void)ws_size;
  const float* x = (const float*)d_in[0];
  const float* Wf = (const float*)d_in[1];
  const float* Wg = (const float*)d_in[2];
  const float* Wh = (const float*)d_in[3];
  const float* gamma = (const float*)d_in[4];

  float* out = (float*)d_out;                                   // [2*4096*256]
  float* beta = out + (size_t)2 * NPOS * CDIM;                  // [2*4096*4096]

  unsigned short* h_t = (unsigned short*)d_ws;                  // [2*256*4096]
  unsigned short* f_hi = h_t + (size_t)2 * CDIM * NPOS;         // [8192*64] each
  unsigned short* f_lo = f_hi + (size_t)2 * NPOS * FDIM;
  unsigned short* g_hi = f_lo + (size_t)2 * NPOS * FDIM;
  unsigned short* g_lo = g_hi + (size_t)2 * NPOS * FDIM;

  hipLaunchKernelGGL(proj_kernel, dim3(2 * NPOS / 16), dim3(256), 0, stream,
                     x, Wf, Wg, Wh, f_hi, f_lo, g_hi, g_lo, h_t);
  hipLaunchKernelGGL(attn_fused_kernel, dim3(512), dim3(512), 0, stream,
                     f_hi, f_lo, g_hi, g_lo, h_t, x, gamma, beta, out);
}

// Round 8
// 169.044 us; speedup vs baseline: 1.5051x; 1.5051x over previous
//
#include <hip/hip_runtime.h>

#define NPOS 4096
#define CDIM 256
#define FDIM 64

typedef short short8 __attribute__((ext_vector_type(8)));
typedef float f32x4 __attribute__((ext_vector_type(4)));

__device__ __forceinline__ unsigned short f2bf(float v) {
  unsigned u = __float_as_uint(v);
  unsigned r = (u + 0x7fffu + ((u >> 16) & 1u)) >> 16;  // RNE
  return (unsigned short)r;
}
__device__ __forceinline__ float bf2f(unsigned short u) {
  return __uint_as_float((unsigned)u << 16);
}
__device__ __forceinline__ short8 as_s8(uint4 u) {
  return *reinterpret_cast<short8*>(&u);
}
__device__ __forceinline__ void gload_lds16(const void* g, void* l) {
  __builtin_amdgcn_global_load_lds(
      (const __attribute__((address_space(1))) unsigned int*)g,
      (__attribute__((address_space(3))) unsigned int*)l, 16, 0, 0);
}

// ---------------------------------------------------------------------------
// Kernel 1: projections.
//   f,g: bf16 hi/lo split planes [8192][64]
//   h_t: (x@Wh)^T bf16 [b][col 256][k 4096], PRE-SWIZZLED: logical 16B chunk c
//        of row `col` stored at position c ^ (col&7)  (for conflict-free PV).
// ---------------------------------------------------------------------------
__global__ __launch_bounds__(256) void proj_kernel(
    const float* __restrict__ x, const float* __restrict__ Wf,
    const float* __restrict__ Wg, const float* __restrict__ Wh,
    unsigned short* __restrict__ f_hi, unsigned short* __restrict__ f_lo,
    unsigned short* __restrict__ g_hi, unsigned short* __restrict__ g_lo,
    unsigned short* __restrict__ h_t) {
  __shared__ float xs[16][CDIM];
  const int row0 = blockIdx.x * 16;
  const int t = threadIdx.x;
  {
    const float4* xv = reinterpret_cast<const float4*>(x + (size_t)row0 * CDIM);
    float4* sv = reinterpret_cast<float4*>(&xs[0][0]);
#pragma unroll
    for (int i = 0; i < 4; ++i) sv[t + 256 * i] = xv[t + 256 * i];
  }
  __syncthreads();
  // h projection -> h_t bf16 swizzled (thread t owns h-col t, 16 k-values)
  {
    float acc[16];
#pragma unroll
    for (int r = 0; r < 16; ++r) acc[r] = 0.f;
    for (int k = 0; k < CDIM; k += 4) {
      const float w0 = Wh[(size_t)(k + 0) * CDIM + t];
      const float w1 = Wh[(size_t)(k + 1) * CDIM + t];
      const float w2 = Wh[(size_t)(k + 2) * CDIM + t];
      const float w3 = Wh[(size_t)(k + 3) * CDIM + t];
#pragma unroll
      for (int r = 0; r < 16; ++r) {
        const float4 xv = *reinterpret_cast<const float4*>(&xs[r][k]);
        float a = acc[r];
        a = fmaf(xv.x, w0, a);
        a = fmaf(xv.y, w1, a);
        a = fmaf(xv.z, w2, a);
        a = fmaf(xv.w, w3, a);
        acc[r] = a;
      }
    }
    const int b = row0 >> 12;
    const int lr = row0 & (NPOS - 1);
    unsigned wd[8];
#pragma unroll
    for (int i = 0; i < 8; ++i)
      wd[i] = (unsigned)f2bf(acc[2 * i]) | ((unsigned)f2bf(acc[2 * i + 1]) << 16);
    uint4* base = reinterpret_cast<uint4*>(h_t + ((size_t)(b * CDIM + t)) * NPOS);
    const int m = t & 7;
    const int c0 = lr >> 3;   // even
    base[c0 ^ m] = make_uint4(wd[0], wd[1], wd[2], wd[3]);
    base[(c0 + 1) ^ m] = make_uint4(wd[4], wd[5], wd[6], wd[7]);
  }
  // f,g projections with hi/lo bf16 split
  {
    const int col = t & 63;
    const int rb = (t >> 6) * 4;
    float af[4] = {0.f, 0.f, 0.f, 0.f};
    float ag[4] = {0.f, 0.f, 0.f, 0.f};
    for (int k = 0; k < CDIM; k += 4) {
      const float wf0 = Wf[(size_t)(k + 0) * FDIM + col];
      const float wf1 = Wf[(size_t)(k + 1) * FDIM + col];
      const float wf2 = Wf[(size_t)(k + 2) * FDIM + col];
      const float wf3 = Wf[(size_t)(k + 3) * FDIM + col];
      const float wg0 = Wg[(size_t)(k + 0) * FDIM + col];
      const float wg1 = Wg[(size_t)(k + 1) * FDIM + col];
      const float wg2 = Wg[(size_t)(k + 2) * FDIM + col];
      const float wg3 = Wg[(size_t)(k + 3) * FDIM + col];
#pragma unroll
      for (int r = 0; r < 4; ++r) {
        const float4 xv = *reinterpret_cast<const float4*>(&xs[rb + r][k]);
        float a = af[r], bb = ag[r];
        a = fmaf(xv.x, wf0, a); a = fmaf(xv.y, wf1, a);
        a = fmaf(xv.z, wf2, a); a = fmaf(xv.w, wf3, a);
        bb = fmaf(xv.x, wg0, bb); bb = fmaf(xv.y, wg1, bb);
        bb = fmaf(xv.z, wg2, bb); bb = fmaf(xv.w, wg3, bb);
        af[r] = a; ag[r] = bb;
      }
    }
#pragma unroll
    for (int r = 0; r < 4; ++r) {
      const size_t o = (size_t)(row0 + rb + r) * FDIM + col;
      const unsigned short fh = f2bf(af[r]);
      const unsigned short gh = f2bf(ag[r]);
      f_hi[o] = fh;
      f_lo[o] = f2bf(af[r] - bf2f(fh));
      g_hi[o] = gh;
      g_lo[o] = f2bf(ag[r] - bf2f(gh));
    }
  }
}

// ---------------------------------------------------------------------------
// Kernel 2: s = g @ f^T via bf16x3 split MFMA (fp32-grade), then
// P = bf16(exp(s)) stored into the SECOND HALF of each beta row of d_out
// (beta rows are 16KB fp32; P rows are the last 8KB, pre-swizzled 16B chunks
// by row&7). l = sum(exp(s)) fp32 -> lrow. m==0 (logits ~±45, fp32-safe).
// ---------------------------------------------------------------------------
__global__ __launch_bounds__(512, 4) void qk_mfma_kernel(
    const unsigned short* __restrict__ f_hi, const unsigned short* __restrict__ f_lo,
    const unsigned short* __restrict__ g_hi, const unsigned short* __restrict__ g_lo,
    float* __restrict__ beta, float* __restrict__ lrow) {
  __shared__ float partl[8][16];
  const int wg = blockIdx.x;
  const int wgid = (wg & 7) * 64 + (wg >> 3);   // bijective XCD chunking (512 wgs)
  const int b = wgid >> 8;
  const int row0 = (wgid & 255) * 16;
  const int t = threadIdx.x;
  const int w = t >> 6;
  const int l = t & 63;
  const int lr = l & 15;
  const int lk = l >> 4;

  short8 ah[2], al[2];
  {
    const unsigned short* gh = g_hi + ((size_t)(b * NPOS + row0 + lr)) * FDIM + lk * 8;
    const unsigned short* gl = g_lo + ((size_t)(b * NPOS + row0 + lr)) * FDIM + lk * 8;
#pragma unroll
    for (int ks = 0; ks < 2; ++ks) {
      ah[ks] = *reinterpret_cast<const short8*>(gh + ks * 32);
      al[ks] = *reinterpret_cast<const short8*>(gl + ks * 32);
    }
  }

  const unsigned short* fhB = f_hi + (size_t)b * NPOS * FDIM + (size_t)lr * FDIM + lk * 8;
  const unsigned short* flB = f_lo + (size_t)b * NPOS * FDIM + (size_t)lr * FDIM + lk * 8;

  float lsum[4] = {0.f, 0.f, 0.f, 0.f};
  unsigned short* Pb = (unsigned short*)(beta + (size_t)b * NPOS * NPOS);

  // prologue: loads for ct = 0
  size_t fo = 0;
  {
    const size_t f0 = (size_t)(w << 9) * FDIM;
    fo = f0;
  }
  uint4 nh0 = *reinterpret_cast<const uint4*>(fhB + fo);
  uint4 nh1 = *reinterpret_cast<const uint4*>(fhB + fo + 32);
  uint4 nl0 = *reinterpret_cast<const uint4*>(flB + fo);
  uint4 nl1 = *reinterpret_cast<const uint4*>(flB + fo + 32);

  for (int ct = 0; ct < 32; ++ct) {
    const uint4 h0 = nh0, h1 = nh1, q0 = nl0, q1 = nl1;
    if (ct < 31) {
      const size_t fn = (size_t)((w << 9) + ((ct + 1) << 4)) * FDIM;
      nh0 = *reinterpret_cast<const uint4*>(fhB + fn);
      nh1 = *reinterpret_cast<const uint4*>(fhB + fn + 32);
      nl0 = *reinterpret_cast<const uint4*>(flB + fn);
      nl1 = *reinterpret_cast<const uint4*>(flB + fn + 32);
    }
    f32x4 acca = {0.f, 0.f, 0.f, 0.f};
    f32x4 accb = {0.f, 0.f, 0.f, 0.f};
    acca = __builtin_amdgcn_mfma_f32_16x16x32_bf16(ah[0], as_s8(h0), acca, 0, 0, 0);
    accb = __builtin_amdgcn_mfma_f32_16x16x32_bf16(al[0], as_s8(h0), accb, 0, 0, 0);
    acca = __builtin_amdgcn_mfma_f32_16x16x32_bf16(ah[0], as_s8(q0), acca, 0, 0, 0);
    accb = __builtin_amdgcn_mfma_f32_16x16x32_bf16(ah[1], as_s8(h1), accb, 0, 0, 0);
    acca = __builtin_amdgcn_mfma_f32_16x16x32_bf16(al[1], as_s8(h1), acca, 0, 0, 0);
    accb = __builtin_amdgcn_mfma_f32_16x16x32_bf16(ah[1], as_s8(q1), accb, 0, 0, 0);
    const f32x4 acc = acca + accb;
    const int col0 = (w << 9) + (ct << 4);
    const int col = col0 + lr;
#pragma unroll
    for (int r = 0; r < 4; ++r) {
      const float e = __expf(acc[r]);
      lsum[r] += e;
      const int grow = row0 + lk * 4 + r;
      unsigned short* prow = Pb + (size_t)grow * (2 * NPOS) + NPOS;
      prow[(((col >> 3) ^ (grow & 7)) << 3) | (col & 7)] = f2bf(e);
    }
  }

#pragma unroll
  for (int off = 1; off < 16; off <<= 1) {
#pragma unroll
    for (int r = 0; r < 4; ++r) lsum[r] += __shfl_xor(lsum[r], off);
  }
  if (lr == 0) {
#pragma unroll
    for (int r = 0; r < 4; ++r) partl[w][lk * 4 + r] = lsum[r];
  }
  __syncthreads();
  if (t < 16) {
    float s = 0.f;
#pragma unroll
    for (int q = 0; q < 8; ++q) s += partl[q][t];
    lrow[(size_t)b * NPOS + row0 + t] = s;
  }
}

// ---------------------------------------------------------------------------
// Kernel 3 (m97-style GEMM): o = beta @ h, beta = P/l written fp32 in stream.
// Block = 32 beta-rows x 256 out-cols, 1024 threads (16 waves, 16r x 32c each).
// A (P bf16, pre-swizzled) and B (h_t bf16, pre-swizzled) staged via
// global_load_lds width-16 (DMA holds in-flight data -> no register pipeline
// for the compiler to collapse), double-buffered, __syncthreads per K-step.
// P lives in the 2nd half of each beta row; reads lead writes by >=1 K-step.
// ---------------------------------------------------------------------------
__global__ __launch_bounds__(1024, 4) void pv_gemm_kernel(
    const unsigned short* __restrict__ h_t, const float* __restrict__ x,
    const float* __restrict__ lrow, const float* __restrict__ gamma,
    float* __restrict__ beta, float* __restrict__ out) {
  __shared__ uint4 Ab[2][32][8];     // P tile  [32 r][8 swizzled chunks]  4 KiB
  __shared__ uint4 Bb[2][256][8];    // h tile  [256 c][8 swizzled chunks] 32 KiB
  __shared__ float linvs[32];

  const int wg = blockIdx.x;
  const int wgid = (wg & 7) * 32 + (wg >> 3);   // bijective XCD chunking (256 wgs)
  const int b = wgid >> 7;
  const int row0 = (wgid & 127) * 32;
  const int t = threadIdx.x;
  const int w = t >> 6;
  const int l = t & 63;
  const int wr = w & 1;     // row half
  const int wc = w >> 1;    // col strip (0..7)

  if (t < 32) linvs[t] = __frcp_rn(lrow[(size_t)b * NPOS + row0 + t]);

  const size_t hoff = (size_t)b * CDIM * NPOS;
  const unsigned short* Pub = (const unsigned short*)(beta + (size_t)b * NPOS * NPOS);

#define STAGE(buf, kt)                                                          \
  do {                                                                          \
    {                                                                           \
      const int slot_ = w * 128 + l;                                            \
      const unsigned short* g_ = h_t + hoff + (size_t)(slot_ >> 3) * NPOS +     \
                                 (size_t)((kt) * 8 + (slot_ & 7)) * 8;          \
      gload_lds16(g_, (unsigned short*)&Bb[buf][0][0] + (size_t)(w * 128) * 8); \
    }                                                                           \
    {                                                                           \
      const int slot_ = w * 128 + 64 + l;                                       \
      const unsigned short* g_ = h_t + hoff + (size_t)(slot_ >> 3) * NPOS +     \
                                 (size_t)((kt) * 8 + (slot_ & 7)) * 8;          \
      gload_lds16(g_, (unsigned short*)&Bb[buf][0][0] +                         \
                          (size_t)(w * 128 + 64) * 8);                          \
    }                                                                           \
    if (t < 256) {                                                              \
      const unsigned short* g_ = Pub + (size_t)(row0 + (t >> 3)) * (2 * NPOS) + \
                                 NPOS + (size_t)((kt) * 8 + (t & 7)) * 8;       \
      gload_lds16(g_, (unsigned short*)&Ab[buf][0][0] + (size_t)(w * 64) * 8);  \
    }                                                                           \
  } while (0)

  f32x4 acc0 = {0.f, 0.f, 0.f, 0.f}, acc1 = {0.f, 0.f, 0.f, 0.f};
  const int ar = wr * 16 + (l & 15);   // local A row 0..31
  const int lk = l >> 4;
  const int c0 = wc * 32 + (l & 15);
  const int c1 = c0 + 16;
  const int brow = t >> 5;             // beta-write row 0..31
  const int jj = t & 31;               // beta-write k-pair

  STAGE(0, 0);
  __syncthreads();

  int buf = 0;
  for (int kt = 0; kt < 64; ++kt) {
    if (kt < 63) STAGE(buf ^ 1, kt + 1);
    // ---- MFMA: K=64 as 2 k-steps of 32
    {
      const uint4 a0 = Ab[buf][ar][lk ^ (ar & 7)];
      const uint4 a1 = Ab[buf][ar][(4 + lk) ^ (ar & 7)];
      const uint4 b00 = Bb[buf][c0][lk ^ (c0 & 7)];
      const uint4 b01 = Bb[buf][c1][lk ^ (c1 & 7)];
      const uint4 b10 = Bb[buf][c0][(4 + lk) ^ (c0 & 7)];
      const uint4 b11 = Bb[buf][c1][(4 + lk) ^ (c1 & 7)];
      acc0 = __builtin_amdgcn_mfma_f32_16x16x32_bf16(as_s8(a0), as_s8(b00), acc0, 0, 0, 0);
      acc1 = __builtin_amdgcn_mfma_f32_16x16x32_bf16(as_s8(a0), as_s8(b01), acc1, 0, 0, 0);
      acc0 = __builtin_amdgcn_mfma_f32_16x16x32_bf16(as_s8(a1), as_s8(b10), acc0, 0, 0, 0);
      acc1 = __builtin_amdgcn_mfma_f32_16x16x32_bf16(as_s8(a1), as_s8(b11), acc1, 0, 0, 0);
    }
    // ---- beta write: 2 elems/thread from staged A tile
    {
      const float il = linvs[brow];
      const unsigned* arow = reinterpret_cast<const unsigned*>(&Ab[buf][brow][0]);
      const unsigned u = arow[(((jj >> 2) ^ (brow & 7)) << 2) | (jj & 3)];
      float2 v;
      v.x = bf2f((unsigned short)(u & 0xffffu)) * il;
      v.y = bf2f((unsigned short)(u >> 16)) * il;
      *reinterpret_cast<float2*>(beta + (size_t)(b * NPOS + row0 + brow) * NPOS +
                                 (size_t)kt * 64 + jj * 2) = v;
    }
    __syncthreads();
    buf ^= 1;
  }
#undef STAGE

  // epilogue: out = gamma*o/l + x ; C/D: col=lane&15, row=(lane>>4)*4+reg
  const float gam = gamma[0];
#pragma unroll
  for (int r = 0; r < 4; ++r) {
    const int lrr = wr * 16 + (l >> 4) * 4 + r;
    const int orow = row0 + lrr;
    const float sc = gam * linvs[lrr];
    const size_t i0 = ((size_t)b * NPOS + orow) * CDIM + wc * 32 + (l & 15);
    out[i0] = fmaf(sc, acc0[r], x[i0]);
    out[i0 + 16] = fmaf(sc, acc1[r], x[i0 + 16]);
  }
}

extern "C" void kernel_launch(void* const* d_in, const int* in_sizes, int n_in,
                              void* d_out, int out_size, void* d_ws, size_t ws_size,
                              hipStream_t stream) {
  (void)in_sizes; (void)n_in; (void)out_size; (void)ws_size;
  const float* x = (const float*)d_in[0];
  const float* Wf = (const float*)d_in[1];
  const float* Wg = (const float*)d_in[2];
  const float* Wh = (const float*)d_in[3];
  const float* gamma = (const float*)d_in[4];

  float* out = (float*)d_out;                                   // [2*4096*256]
  float* beta = out + (size_t)2 * NPOS * CDIM;                  // [2*4096*4096]

  unsigned short* h_t = (unsigned short*)d_ws;                  // [2*256*4096]
  unsigned short* f_hi = h_t + (size_t)2 * CDIM * NPOS;         // [8192*64] each
  unsigned short* f_lo = f_hi + (size_t)2 * NPOS * FDIM;
  unsigned short* g_hi = f_lo + (size_t)2 * NPOS * FDIM;
  unsigned short* g_lo = g_hi + (size_t)2 * NPOS * FDIM;
  float* lrow = (float*)(g_lo + (size_t)2 * NPOS * FDIM);       // [8192]

  hipLaunchKernelGGL(proj_kernel, dim3(2 * NPOS / 16), dim3(256), 0, stream,
                     x, Wf, Wg, Wh, f_hi, f_lo, g_hi, g_lo, h_t);
  hipLaunchKernelGGL(qk_mfma_kernel, dim3(512), dim3(512), 0, stream,
                     f_hi, f_lo, g_hi, g_lo, beta, lrow);
  hipLaunchKernelGGL(pv_gemm_kernel, dim3(256), dim3(1024), 0, stream,
                     h_t, x, lrow, gamma, beta, out);
}

// Round 9
// 168.092 us; speedup vs baseline: 1.5136x; 1.0057x over previous
//
#include <hip/hip_runtime.h>

#define NPOS 4096
#define CDIM 256
#define FDIM 64

typedef short short8 __attribute__((ext_vector_type(8)));
typedef float f32x4 __attribute__((ext_vector_type(4)));

__device__ __forceinline__ unsigned short f2bf(float v) {
  unsigned u = __float_as_uint(v);
  unsigned r = (u + 0x7fffu + ((u >> 16) & 1u)) >> 16;  // RNE
  return (unsigned short)r;
}
__device__ __forceinline__ float bf2f(unsigned short u) {
  return __uint_as_float((unsigned)u << 16);
}
__device__ __forceinline__ short8 as_s8(uint4 u) {
  return *reinterpret_cast<short8*>(&u);
}
__device__ __forceinline__ void gload_lds16(const void* g, void* l) {
  __builtin_amdgcn_global_load_lds(
      (const __attribute__((address_space(1))) unsigned int*)g,
      (__attribute__((address_space(3))) unsigned int*)l, 16, 0, 0);
}

// ---------------------------------------------------------------------------
// Kernel 1: projections.
//   f,g: bf16 hi/lo split planes [8192][64]
//   h_t: (x@Wh)^T bf16 [b][col 256][k 4096], PRE-SWIZZLED: logical 16B chunk c
//        of row `col` stored at position c ^ (col&7)  (for conflict-free PV).
// ---------------------------------------------------------------------------
__global__ __launch_bounds__(256) void proj_kernel(
    const float* __restrict__ x, const float* __restrict__ Wf,
    const float* __restrict__ Wg, const float* __restrict__ Wh,
    unsigned short* __restrict__ f_hi, unsigned short* __restrict__ f_lo,
    unsigned short* __restrict__ g_hi, unsigned short* __restrict__ g_lo,
    unsigned short* __restrict__ h_t) {
  __shared__ float xs[16][CDIM];
  const int row0 = blockIdx.x * 16;
  const int t = threadIdx.x;
  {
    const float4* xv = reinterpret_cast<const float4*>(x + (size_t)row0 * CDIM);
    float4* sv = reinterpret_cast<float4*>(&xs[0][0]);
#pragma unroll
    for (int i = 0; i < 4; ++i) sv[t + 256 * i] = xv[t + 256 * i];
  }
  __syncthreads();
  // h projection -> h_t bf16 swizzled (thread t owns h-col t, 16 k-values)
  {
    float acc[16];
#pragma unroll
    for (int r = 0; r < 16; ++r) acc[r] = 0.f;
    for (int k = 0; k < CDIM; k += 4) {
      const float w0 = Wh[(size_t)(k + 0) * CDIM + t];
      const float w1 = Wh[(size_t)(k + 1) * CDIM + t];
      const float w2 = Wh[(size_t)(k + 2) * CDIM + t];
      const float w3 = Wh[(size_t)(k + 3) * CDIM + t];
#pragma unroll
      for (int r = 0; r < 16; ++r) {
        const float4 xv = *reinterpret_cast<const float4*>(&xs[r][k]);
        float a = acc[r];
        a = fmaf(xv.x, w0, a);
        a = fmaf(xv.y, w1, a);
        a = fmaf(xv.z, w2, a);
        a = fmaf(xv.w, w3, a);
        acc[r] = a;
      }
    }
    const int b = row0 >> 12;
    const int lr = row0 & (NPOS - 1);
    unsigned wd[8];
#pragma unroll
    for (int i = 0; i < 8; ++i)
      wd[i] = (unsigned)f2bf(acc[2 * i]) | ((unsigned)f2bf(acc[2 * i + 1]) << 16);
    uint4* base = reinterpret_cast<uint4*>(h_t + ((size_t)(b * CDIM + t)) * NPOS);
    const int m = t & 7;
    const int c0 = lr >> 3;   // even
    base[c0 ^ m] = make_uint4(wd[0], wd[1], wd[2], wd[3]);
    base[(c0 + 1) ^ m] = make_uint4(wd[4], wd[5], wd[6], wd[7]);
  }
  // f,g projections with hi/lo bf16 split
  {
    const int col = t & 63;
    const int rb = (t >> 6) * 4;
    float af[4] = {0.f, 0.f, 0.f, 0.f};
    float ag[4] = {0.f, 0.f, 0.f, 0.f};
    for (int k = 0; k < CDIM; k += 4) {
      const float wf0 = Wf[(size_t)(k + 0) * FDIM + col];
      const float wf1 = Wf[(size_t)(k + 1) * FDIM + col];
      const float wf2 = Wf[(size_t)(k + 2) * FDIM + col];
      const float wf3 = Wf[(size_t)(k + 3) * FDIM + col];
      const float wg0 = Wg[(size_t)(k + 0) * FDIM + col];
      const float wg1 = Wg[(size_t)(k + 1) * FDIM + col];
      const float wg2 = Wg[(size_t)(k + 2) * FDIM + col];
      const float wg3 = Wg[(size_t)(k + 3) * FDIM + col];
#pragma unroll
      for (int r = 0; r < 4; ++r) {
        const float4 xv = *reinterpret_cast<const float4*>(&xs[rb + r][k]);
        float a = af[r], bb = ag[r];
        a = fmaf(xv.x, wf0, a); a = fmaf(xv.y, wf1, a);
        a = fmaf(xv.z, wf2, a); a = fmaf(xv.w, wf3, a);
        bb = fmaf(xv.x, wg0, bb); bb = fmaf(xv.y, wg1, bb);
        bb = fmaf(xv.z, wg2, bb); bb = fmaf(xv.w, wg3, bb);
        af[r] = a; ag[r] = bb;
      }
    }
#pragma unroll
    for (int r = 0; r < 4; ++r) {
      const size_t o = (size_t)(row0 + rb + r) * FDIM + col;
      const unsigned short fh = f2bf(af[r]);
      const unsigned short gh = f2bf(ag[r]);
      f_hi[o] = fh;
      f_lo[o] = f2bf(af[r] - bf2f(fh));
      g_hi[o] = gh;
      g_lo[o] = f2bf(ag[r] - bf2f(gh));
    }
  }
}

// ---------------------------------------------------------------------------
// Kernel 2 (v2, swapped operands): s = g @ f^T via bf16x3 MFMA with A=f, B=g
// so each lane holds 4 CONSECUTIVE beta-cols of ONE beta-row (r7-validated
// C/D mapping): P = bf16(exp(s)) is then ONE aligned uint2 store per tile
// (was 4 scattered 2B stores). P goes into the 2nd half of each beta row,
// physical layout identical to r8 (swizzled 16B chunks by row&7).
// l = sum(exp(s)) -> lrow. m==0 (logits ~±45, fp32-safe).
// ---------------------------------------------------------------------------
__global__ __launch_bounds__(512, 4) void qk_mfma_kernel(
    const unsigned short* __restrict__ f_hi, const unsigned short* __restrict__ f_lo,
    const unsigned short* __restrict__ g_hi, const unsigned short* __restrict__ g_lo,
    float* __restrict__ beta, float* __restrict__ lrow) {
  __shared__ float partl[8][16];
  const int wg = blockIdx.x;
  const int wgid = (wg & 7) * 64 + (wg >> 3);   // bijective XCD chunking (512 wgs)
  const int b = wgid >> 8;
  const int row0 = (wgid & 255) * 16;
  const int t = threadIdx.x;
  const int w = t >> 6;
  const int l = t & 63;
  const int lr = l & 15;   // beta-row (C col after swap) AND f/g fragment row
  const int lk = l >> 4;   // k-octet; after swap also beta-col quad selector

  // g fragments (B operand after swap): beta-rows row0..row0+15
  short8 gh[2], gl[2];
  {
    const unsigned short* gH = g_hi + ((size_t)(b * NPOS + row0 + lr)) * FDIM + lk * 8;
    const unsigned short* gL = g_lo + ((size_t)(b * NPOS + row0 + lr)) * FDIM + lk * 8;
#pragma unroll
    for (int ks = 0; ks < 2; ++ks) {
      gh[ks] = *reinterpret_cast<const short8*>(gH + ks * 32);
      gl[ks] = *reinterpret_cast<const short8*>(gL + ks * 32);
    }
  }

  const unsigned short* fhB = f_hi + (size_t)b * NPOS * FDIM + (size_t)lr * FDIM + lk * 8;
  const unsigned short* flB = f_lo + (size_t)b * NPOS * FDIM + (size_t)lr * FDIM + lk * 8;

  float lsum = 0.f;
  unsigned short* Pb = (unsigned short*)(beta + (size_t)b * NPOS * NPOS);
  // this lane's P row pointer (row = row0 + lr, fixed for the whole kernel)
  unsigned short* prow = Pb + (size_t)(row0 + lr) * (2 * NPOS) + NPOS;
  const int rsw = lr & 7;

  // prologue: loads for ct = 0
  const size_t fo = (size_t)(w << 9) * FDIM;
  uint4 nh0 = *reinterpret_cast<const uint4*>(fhB + fo);
  uint4 nh1 = *reinterpret_cast<const uint4*>(fhB + fo + 32);
  uint4 nl0 = *reinterpret_cast<const uint4*>(flB + fo);
  uint4 nl1 = *reinterpret_cast<const uint4*>(flB + fo + 32);

  for (int ct = 0; ct < 32; ++ct) {
    const uint4 h0 = nh0, h1 = nh1, q0 = nl0, q1 = nl1;
    if (ct < 31) {
      const size_t fn = (size_t)((w << 9) + ((ct + 1) << 4)) * FDIM;
      nh0 = *reinterpret_cast<const uint4*>(fhB + fn);
      nh1 = *reinterpret_cast<const uint4*>(fhB + fn + 32);
      nl0 = *reinterpret_cast<const uint4*>(flB + fn);
      nl1 = *reinterpret_cast<const uint4*>(flB + fn + 32);
    }
    f32x4 acca = {0.f, 0.f, 0.f, 0.f};
    f32x4 accb = {0.f, 0.f, 0.f, 0.f};
    // A = f tile (M = beta-cols), B = g (N = beta-rows)
    acca = __builtin_amdgcn_mfma_f32_16x16x32_bf16(as_s8(h0), gh[0], acca, 0, 0, 0);
    accb = __builtin_amdgcn_mfma_f32_16x16x32_bf16(as_s8(h0), gl[0], accb, 0, 0, 0);
    acca = __builtin_amdgcn_mfma_f32_16x16x32_bf16(as_s8(q0), gh[0], acca, 0, 0, 0);
    accb = __builtin_amdgcn_mfma_f32_16x16x32_bf16(as_s8(h1), gh[1], accb, 0, 0, 0);
    acca = __builtin_amdgcn_mfma_f32_16x16x32_bf16(as_s8(q1), gh[1], acca, 0, 0, 0);
    accb = __builtin_amdgcn_mfma_f32_16x16x32_bf16(as_s8(h1), gl[1], accb, 0, 0, 0);
    const f32x4 acc = acca + accb;
    // lane holds beta-row row0+lr, beta-cols cq..cq+3 (consecutive)
    const int cq = (w << 9) + (ct << 4) + lk * 4;
    const float e0 = __expf(acc[0]);
    const float e1 = __expf(acc[1]);
    const float e2 = __expf(acc[2]);
    const float e3 = __expf(acc[3]);
    lsum += (e0 + e1) + (e2 + e3);
    uint2 pk;
    pk.x = (unsigned)f2bf(e0) | ((unsigned)f2bf(e1) << 16);
    pk.y = (unsigned)f2bf(e2) | ((unsigned)f2bf(e3) << 16);
    const int sidx = (((cq >> 3) ^ rsw) << 3) | (cq & 7);
    *reinterpret_cast<uint2*>(prow + sidx) = pk;
  }

  // row sums: lanes {l, l^16, l^32, l^48} share beta-row lr
  lsum += __shfl_xor(lsum, 16);
  lsum += __shfl_xor(lsum, 32);
  if (l < 16) partl[w][l] = lsum;
  __syncthreads();
  if (t < 16) {
    float s = 0.f;
#pragma unroll
    for (int q = 0; q < 8; ++q) s += partl[q][t];
    lrow[(size_t)b * NPOS + row0 + t] = s;
  }
}

// ---------------------------------------------------------------------------
// Kernel 3 (m97-style GEMM): o = beta @ h, beta = P/l written fp32 in stream.
// Block = 32 beta-rows x 256 out-cols, 1024 threads (16 waves, 16r x 32c each).
// A (P bf16, pre-swizzled) and B (h_t bf16, pre-swizzled) staged via
// global_load_lds width-16, double-buffered, __syncthreads per K-step.
// ---------------------------------------------------------------------------
__global__ __launch_bounds__(1024, 4) void pv_gemm_kernel(
    const unsigned short* __restrict__ h_t, const float* __restrict__ x,
    const float* __restrict__ lrow, const float* __restrict__ gamma,
    float* __restrict__ beta, float* __restrict__ out) {
  __shared__ uint4 Ab[2][32][8];     // P tile  [32 r][8 swizzled chunks]  4 KiB
  __shared__ uint4 Bb[2][256][8];    // h tile  [256 c][8 swizzled chunks] 32 KiB
  __shared__ float linvs[32];

  const int wg = blockIdx.x;
  const int wgid = (wg & 7) * 32 + (wg >> 3);   // bijective XCD chunking (256 wgs)
  const int b = wgid >> 7;
  const int row0 = (wgid & 127) * 32;
  const int t = threadIdx.x;
  const int w = t >> 6;
  const int l = t & 63;
  const int wr = w & 1;     // row half
  const int wc = w >> 1;    // col strip (0..7)

  if (t < 32) linvs[t] = __frcp_rn(lrow[(size_t)b * NPOS + row0 + t]);

  const size_t hoff = (size_t)b * CDIM * NPOS;
  const unsigned short* Pub = (const unsigned short*)(beta + (size_t)b * NPOS * NPOS);

#define STAGE(buf, kt)                                                          \
  do {                                                                          \
    {                                                                           \
      const int slot_ = w * 128 + l;                                            \
      const unsigned short* g_ = h_t + hoff + (size_t)(slot_ >> 3) * NPOS +     \
                                 (size_t)((kt) * 8 + (slot_ & 7)) * 8;          \
      gload_lds16(g_, (unsigned short*)&Bb[buf][0][0] + (size_t)(w * 128) * 8); \
    }                                                                           \
    {                                                                           \
      const int slot_ = w * 128 + 64 + l;                                       \
      const unsigned short* g_ = h_t + hoff + (size_t)(slot_ >> 3) * NPOS +     \
                                 (size_t)((kt) * 8 + (slot_ & 7)) * 8;          \
      gload_lds16(g_, (unsigned short*)&Bb[buf][0][0] +                         \
                          (size_t)(w * 128 + 64) * 8);                          \
    }                                                                           \
    if (t < 256) {                                                              \
      const unsigned short* g_ = Pub + (size_t)(row0 + (t >> 3)) * (2 * NPOS) + \
                                 NPOS + (size_t)((kt) * 8 + (t & 7)) * 8;       \
      gload_lds16(g_, (unsigned short*)&Ab[buf][0][0] + (size_t)(w * 64) * 8);  \
    }                                                                           \
  } while (0)

  f32x4 acc0 = {0.f, 0.f, 0.f, 0.f}, acc1 = {0.f, 0.f, 0.f, 0.f};
  const int ar = wr * 16 + (l & 15);   // local A row 0..31
  const int lk = l >> 4;
  const int c0 = wc * 32 + (l & 15);
  const int c1 = c0 + 16;
  const int brow = t >> 5;             // beta-write row 0..31
  const int jj = t & 31;               // beta-write k-pair

  STAGE(0, 0);
  __syncthreads();

  int buf = 0;
  for (int kt = 0; kt < 64; ++kt) {
    if (kt < 63) STAGE(buf ^ 1, kt + 1);
    // ---- MFMA: K=64 as 2 k-steps of 32
    {
      const uint4 a0 = Ab[buf][ar][lk ^ (ar & 7)];
      const uint4 a1 = Ab[buf][ar][(4 + lk) ^ (ar & 7)];
      const uint4 b00 = Bb[buf][c0][lk ^ (c0 & 7)];
      const uint4 b01 = Bb[buf][c1][lk ^ (c1 & 7)];
      const uint4 b10 = Bb[buf][c0][(4 + lk) ^ (c0 & 7)];
      const uint4 b11 = Bb[buf][c1][(4 + lk) ^ (c1 & 7)];
      acc0 = __builtin_amdgcn_mfma_f32_16x16x32_bf16(as_s8(a0), as_s8(b00), acc0, 0, 0, 0);
      acc1 = __builtin_amdgcn_mfma_f32_16x16x32_bf16(as_s8(a0), as_s8(b01), acc1, 0, 0, 0);
      acc0 = __builtin_amdgcn_mfma_f32_16x16x32_bf16(as_s8(a1), as_s8(b10), acc0, 0, 0, 0);
      acc1 = __builtin_amdgcn_mfma_f32_16x16x32_bf16(as_s8(a1), as_s8(b11), acc1, 0, 0, 0);
    }
    // ---- beta write: 2 elems/thread from staged A tile
    {
      const float il = linvs[brow];
      const unsigned* arow = reinterpret_cast<const unsigned*>(&Ab[buf][brow][0]);
      const unsigned u = arow[(((jj >> 2) ^ (brow & 7)) << 2) | (jj & 3)];
      float2 v;
      v.x = bf2f((unsigned short)(u & 0xffffu)) * il;
      v.y = bf2f((unsigned short)(u >> 16)) * il;
      *reinterpret_cast<float2*>(beta + (size_t)(b * NPOS + row0 + brow) * NPOS +
                                 (size_t)kt * 64 + jj * 2) = v;
    }
    __syncthreads();
    buf ^= 1;
  }
#undef STAGE

  // epilogue: out = gamma*o/l + x ; C/D: col=lane&15, row=(lane>>4)*4+reg
  const float gam = gamma[0];
#pragma unroll
  for (int r = 0; r < 4; ++r) {
    const int lrr = wr * 16 + (l >> 4) * 4 + r;
    const int orow = row0 + lrr;
    const float sc = gam * linvs[lrr];
    const size_t i0 = ((size_t)b * NPOS + orow) * CDIM + wc * 32 + (l & 15);
    out[i0] = fmaf(sc, acc0[r], x[i0]);
    out[i0 + 16] = fmaf(sc, acc1[r], x[i0 + 16]);
  }
}

extern "C" void kernel_launch(void* const* d_in, const int* in_sizes, int n_in,
                              void* d_out, int out_size, void* d_ws, size_t ws_size,
                              hipStream_t stream) {
  (void)in_sizes; (void)n_in; (void)out_size; (void)ws_size;
  const float* x = (const float*)d_in[0];
  const float* Wf = (const float*)d_in[1];
  const float* Wg = (const float*)d_in[2];
  const float* Wh = (const float*)d_in[3];
  const float* gamma = (const float*)d_in[4];

  float* out = (float*)d_out;                                   // [2*4096*256]
  float* beta = out + (size_t)2 * NPOS * CDIM;                  // [2*4096*4096]

  unsigned short* h_t = (unsigned short*)d_ws;                  // [2*256*4096]
  unsigned short* f_hi = h_t + (size_t)2 * CDIM * NPOS;         // [8192*64] each
  unsigned short* f_lo = f_hi + (size_t)2 * NPOS * FDIM;
  unsigned short* g_hi = f_lo + (size_t)2 * NPOS * FDIM;
  unsigned short* g_lo = g_hi + (size_t)2 * NPOS * FDIM;
  float* lrow = (float*)(g_lo + (size_t)2 * NPOS * FDIM);       // [8192]

  hipLaunchKernelGGL(proj_kernel, dim3(2 * NPOS / 16), dim3(256), 0, stream,
                     x, Wf, Wg, Wh, f_hi, f_lo, g_hi, g_lo, h_t);
  hipLaunchKernelGGL(qk_mfma_kernel, dim3(512), dim3(512), 0, stream,
                     f_hi, f_lo, g_hi, g_lo, beta, lrow);
  hipLaunchKernelGGL(pv_gemm_kernel, dim3(256), dim3(1024), 0, stream,
                     h_t, x, lrow, gamma, beta, out);
}

// Round 10
// 136.631 us; speedup vs baseline: 1.8622x; 1.2303x over previous
//
#include <hip/hip_runtime.h>

#define NPOS 4096
#define CDIM 256
#define FDIM 64

typedef short short8 __attribute__((ext_vector_type(8)));
typedef float f32x4 __attribute__((ext_vector_type(4)));

__device__ __forceinline__ unsigned short f2bf(float v) {
  unsigned u = __float_as_uint(v);
  unsigned r = (u + 0x7fffu + ((u >> 16) & 1u)) >> 16;  // RNE
  return (unsigned short)r;
}
__device__ __forceinline__ float bf2f(unsigned short u) {
  return __uint_as_float((unsigned)u << 16);
}
__device__ __forceinline__ short8 as_s8(uint4 u) {
  return *reinterpret_cast<short8*>(&u);
}
__device__ __forceinline__ void gload_lds16(const void* g, void* l) {
  __builtin_amdgcn_global_load_lds(
      (const __attribute__((address_space(1))) unsigned int*)g,
      (__attribute__((address_space(3))) unsigned int*)l, 16, 0, 0);
}

// ---------------------------------------------------------------------------
// Kernel 1: projections.
//   f,g: bf16 hi/lo split planes [8192][64]; f planes PRE-SWIZZLED (16B chunk
//        c of row r stored at c^(r&7)) for qk's DMA->LDS staging. g linear.
//   h_t: (x@Wh)^T bf16 [b][col 256][k 4096], pre-swizzled the same way.
// ---------------------------------------------------------------------------
__global__ __launch_bounds__(256) void proj_kernel(
    const float* __restrict__ x, const float* __restrict__ Wf,
    const float* __restrict__ Wg, const float* __restrict__ Wh,
    unsigned short* __restrict__ f_hi, unsigned short* __restrict__ f_lo,
    unsigned short* __restrict__ g_hi, unsigned short* __restrict__ g_lo,
    unsigned short* __restrict__ h_t) {
  __shared__ float xs[16][CDIM];
  const int row0 = blockIdx.x * 16;
  const int t = threadIdx.x;
  {
    const float4* xv = reinterpret_cast<const float4*>(x + (size_t)row0 * CDIM);
    float4* sv = reinterpret_cast<float4*>(&xs[0][0]);
#pragma unroll
    for (int i = 0; i < 4; ++i) sv[t + 256 * i] = xv[t + 256 * i];
  }
  __syncthreads();
  // h projection -> h_t bf16 swizzled (thread t owns h-col t, 16 k-values)
  {
    float acc[16];
#pragma unroll
    for (int r = 0; r < 16; ++r) acc[r] = 0.f;
    for (int k = 0; k < CDIM; k += 4) {
      const float w0 = Wh[(size_t)(k + 0) * CDIM + t];
      const float w1 = Wh[(size_t)(k + 1) * CDIM + t];
      const float w2 = Wh[(size_t)(k + 2) * CDIM + t];
      const float w3 = Wh[(size_t)(k + 3) * CDIM + t];
#pragma unroll
      for (int r = 0; r < 16; ++r) {
        const float4 xv = *reinterpret_cast<const float4*>(&xs[r][k]);
        float a = acc[r];
        a = fmaf(xv.x, w0, a);
        a = fmaf(xv.y, w1, a);
        a = fmaf(xv.z, w2, a);
        a = fmaf(xv.w, w3, a);
        acc[r] = a;
      }
    }
    const int b = row0 >> 12;
    const int lr = row0 & (NPOS - 1);
    unsigned wd[8];
#pragma unroll
    for (int i = 0; i < 8; ++i)
      wd[i] = (unsigned)f2bf(acc[2 * i]) | ((unsigned)f2bf(acc[2 * i + 1]) << 16);
    uint4* base = reinterpret_cast<uint4*>(h_t + ((size_t)(b * CDIM + t)) * NPOS);
    const int m = t & 7;
    const int c0 = lr >> 3;   // even
    base[c0 ^ m] = make_uint4(wd[0], wd[1], wd[2], wd[3]);
    base[(c0 + 1) ^ m] = make_uint4(wd[4], wd[5], wd[6], wd[7]);
  }
  // f,g projections with hi/lo bf16 split; f planes stored pre-swizzled
  {
    const int col = t & 63;
    const int rb = (t >> 6) * 4;
    const int colq = col >> 3, cwi = col & 7;
    float af[4] = {0.f, 0.f, 0.f, 0.f};
    float ag[4] = {0.f, 0.f, 0.f, 0.f};
    for (int k = 0; k < CDIM; k += 4) {
      const float wf0 = Wf[(size_t)(k + 0) * FDIM + col];
      const float wf1 = Wf[(size_t)(k + 1) * FDIM + col];
      const float wf2 = Wf[(size_t)(k + 2) * FDIM + col];
      const float wf3 = Wf[(size_t)(k + 3) * FDIM + col];
      const float wg0 = Wg[(size_t)(k + 0) * FDIM + col];
      const float wg1 = Wg[(size_t)(k + 1) * FDIM + col];
      const float wg2 = Wg[(size_t)(k + 2) * FDIM + col];
      const float wg3 = Wg[(size_t)(k + 3) * FDIM + col];
#pragma unroll
      for (int r = 0; r < 4; ++r) {
        const float4 xv = *reinterpret_cast<const float4*>(&xs[rb + r][k]);
        float a = af[r], bb = ag[r];
        a = fmaf(xv.x, wf0, a); a = fmaf(xv.y, wf1, a);
        a = fmaf(xv.z, wf2, a); a = fmaf(xv.w, wf3, a);
        bb = fmaf(xv.x, wg0, bb); bb = fmaf(xv.y, wg1, bb);
        bb = fmaf(xv.z, wg2, bb); bb = fmaf(xv.w, wg3, bb);
        af[r] = a; ag[r] = bb;
      }
    }
#pragma unroll
    for (int r = 0; r < 4; ++r) {
      const int row = row0 + rb + r;
      const int ph = ((colq ^ (row & 7)) << 3) | cwi;   // pre-swizzled f pos
      const size_t of = (size_t)row * FDIM + ph;
      const size_t og = (size_t)row * FDIM + col;       // g stays linear
      const unsigned short fh = f2bf(af[r]);
      const unsigned short gh = f2bf(ag[r]);
      f_hi[of] = fh;
      f_lo[of] = f2bf(af[r] - bf2f(fh));
      g_hi[og] = gh;
      g_lo[og] = f2bf(ag[r] - bf2f(gh));
    }
  }
}

// ---------------------------------------------------------------------------
// Kernel 2 (v3, m97-style): s = g @ f^T via bf16x3 MFMA, swapped operands
// (A=f, B=g). f tiles (128 cols x 64k, hi+lo = 32 KB) staged via
// global_load_lds, double-buffered, one __syncthreads per tile — the DMA
// holds in-flight data so there is no register pipeline for the compiler to
// collapse (the r4-r9 lesson; same structure that fixed pv in r8).
// Each of 8 waves computes one 16-col tile/step from LDS (4 ds_read_b128).
// P = bf16(exp(s)) -> 2nd half of beta rows (swizzled), l -> lrow.
// ---------------------------------------------------------------------------
__global__ __launch_bounds__(512, 4) void qk_mfma_kernel(
    const unsigned short* __restrict__ f_hi, const unsigned short* __restrict__ f_lo,
    const unsigned short* __restrict__ g_hi, const unsigned short* __restrict__ g_lo,
    float* __restrict__ beta, float* __restrict__ lrow) {
  __shared__ uint4 Fh[2][128][8];   // 32 KB
  __shared__ uint4 Fl[2][128][8];   // 32 KB
  __shared__ float partl[8][16];

  const int wg = blockIdx.x;
  const int wgid = (wg & 7) * 64 + (wg >> 3);   // bijective XCD chunking (512 wgs)
  const int b = wgid >> 8;
  const int row0 = (wgid & 255) * 16;
  const int t = threadIdx.x;
  const int w = t >> 6;
  const int l = t & 63;
  const int lr = l & 15;   // beta-row; also g fragment row
  const int lk = l >> 4;   // k-octet / beta-col quad selector

  // g fragments (B operand): beta-rows row0..row0+15
  short8 gh[2], gl[2];
  {
    const unsigned short* gH = g_hi + ((size_t)(b * NPOS + row0 + lr)) * FDIM + lk * 8;
    const unsigned short* gL = g_lo + ((size_t)(b * NPOS + row0 + lr)) * FDIM + lk * 8;
#pragma unroll
    for (int ks = 0; ks < 2; ++ks) {
      gh[ks] = *reinterpret_cast<const short8*>(gH + ks * 32);
      gl[ks] = *reinterpret_cast<const short8*>(gL + ks * 32);
    }
  }

  const unsigned short* fbh = f_hi + (size_t)b * NPOS * FDIM;
  const unsigned short* fbl = f_lo + (size_t)b * NPOS * FDIM;

  float lsum = 0.f;
  unsigned short* Pb = (unsigned short*)(beta + (size_t)b * NPOS * NPOS);
  unsigned short* prow = Pb + (size_t)(row0 + lr) * (2 * NPOS) + NPOS;
  const int rsw = lr & 7;

  // stage: 4 gload_lds per thread (2 hi + 2 lo), slots = j*512 + t
#define STAGE(buf, tile)                                                       \
  do {                                                                         \
    const int tile0_ = (tile) * 128;                                           \
    _Pragma("unroll")                                                          \
    for (int j = 0; j < 2; ++j) {                                              \
      const int slot_ = j * 512 + t;                                           \
      const int row_ = slot_ >> 3, ch_ = slot_ & 7;                            \
      gload_lds16(fbh + (size_t)(tile0_ + row_) * FDIM + ch_ * 8,              \
                  (unsigned short*)&Fh[buf][0][0] + (size_t)slot_ * 8);        \
      gload_lds16(fbl + (size_t)(tile0_ + row_) * FDIM + ch_ * 8,              \
                  (unsigned short*)&Fl[buf][0][0] + (size_t)slot_ * 8);        \
    }                                                                          \
  } while (0)

  STAGE(0, 0);
  __syncthreads();

  const int rrA = w * 16 + lr;    // this wave's A row within the 128-col tile
  const int fsw = rrA & 7;
  int buf = 0;
  for (int tile = 0; tile < 32; ++tile) {
    if (tile < 31) STAGE(buf ^ 1, tile + 1);
    // A frags from LDS (logical octets lk, lk+4; physical XOR row&7)
    const uint4 h0 = Fh[buf][rrA][lk ^ fsw];
    const uint4 h1 = Fh[buf][rrA][(lk + 4) ^ fsw];
    const uint4 q0 = Fl[buf][rrA][lk ^ fsw];
    const uint4 q1 = Fl[buf][rrA][(lk + 4) ^ fsw];
    f32x4 acca = {0.f, 0.f, 0.f, 0.f};
    f32x4 accb = {0.f, 0.f, 0.f, 0.f};
    acca = __builtin_amdgcn_mfma_f32_16x16x32_bf16(as_s8(h0), gh[0], acca, 0, 0, 0);
    accb = __builtin_amdgcn_mfma_f32_16x16x32_bf16(as_s8(h0), gl[0], accb, 0, 0, 0);
    acca = __builtin_amdgcn_mfma_f32_16x16x32_bf16(as_s8(q0), gh[0], acca, 0, 0, 0);
    accb = __builtin_amdgcn_mfma_f32_16x16x32_bf16(as_s8(h1), gh[1], accb, 0, 0, 0);
    acca = __builtin_amdgcn_mfma_f32_16x16x32_bf16(as_s8(q1), gh[1], acca, 0, 0, 0);
    accb = __builtin_amdgcn_mfma_f32_16x16x32_bf16(as_s8(h1), gl[1], accb, 0, 0, 0);
    const f32x4 acc = acca + accb;
    // lane: beta-row row0+lr, beta-cols cq..cq+3 (consecutive)
    const int cq = tile * 128 + w * 16 + lk * 4;
    const float e0 = __expf(acc[0]);
    const float e1 = __expf(acc[1]);
    const float e2 = __expf(acc[2]);
    const float e3 = __expf(acc[3]);
    lsum += (e0 + e1) + (e2 + e3);
    uint2 pk;
    pk.x = (unsigned)f2bf(e0) | ((unsigned)f2bf(e1) << 16);
    pk.y = (unsigned)f2bf(e2) | ((unsigned)f2bf(e3) << 16);
    const int sidx = (((cq >> 3) ^ rsw) << 3) | (cq & 7);
    *reinterpret_cast<uint2*>(prow + sidx) = pk;
    __syncthreads();
    buf ^= 1;
  }
#undef STAGE

  // row sums: lanes {l, l^16, l^32, l^48} share beta-row lr
  lsum += __shfl_xor(lsum, 16);
  lsum += __shfl_xor(lsum, 32);
  if (l < 16) partl[w][l] = lsum;
  __syncthreads();
  if (t < 16) {
    float s = 0.f;
#pragma unroll
    for (int q = 0; q < 8; ++q) s += partl[q][t];
    lrow[(size_t)b * NPOS + row0 + t] = s;
  }
}

// ---------------------------------------------------------------------------
// Kernel 3 (m97-style GEMM): o = beta @ h, beta = P/l written fp32 in stream.
// Block = 32 beta-rows x 256 out-cols, 1024 threads (16 waves, 16r x 32c each).
// A (P bf16, pre-swizzled) and B (h_t bf16, pre-swizzled) staged via
// global_load_lds width-16, double-buffered, __syncthreads per K-step.
// ---------------------------------------------------------------------------
__global__ __launch_bounds__(1024, 4) void pv_gemm_kernel(
    const unsigned short* __restrict__ h_t, const float* __restrict__ x,
    const float* __restrict__ lrow, const float* __restrict__ gamma,
    float* __restrict__ beta, float* __restrict__ out) {
  __shared__ uint4 Ab[2][32][8];     // P tile  [32 r][8 swizzled chunks]  4 KiB
  __shared__ uint4 Bb[2][256][8];    // h tile  [256 c][8 swizzled chunks] 32 KiB
  __shared__ float linvs[32];

  const int wg = blockIdx.x;
  const int wgid = (wg & 7) * 32 + (wg >> 3);   // bijective XCD chunking (256 wgs)
  const int b = wgid >> 7;
  const int row0 = (wgid & 127) * 32;
  const int t = threadIdx.x;
  const int w = t >> 6;
  const int l = t & 63;
  const int wr = w & 1;     // row half
  const int wc = w >> 1;    // col strip (0..7)

  if (t < 32) linvs[t] = __frcp_rn(lrow[(size_t)b * NPOS + row0 + t]);

  const size_t hoff = (size_t)b * CDIM * NPOS;
  const unsigned short* Pub = (const unsigned short*)(beta + (size_t)b * NPOS * NPOS);

#define STAGE(buf, kt)                                                          \
  do {                                                                          \
    {                                                                           \
      const int slot_ = w * 128 + l;                                            \
      const unsigned short* g_ = h_t + hoff + (size_t)(slot_ >> 3) * NPOS +     \
                                 (size_t)((kt) * 8 + (slot_ & 7)) * 8;          \
      gload_lds16(g_, (unsigned short*)&Bb[buf][0][0] + (size_t)(w * 128) * 8); \
    }                                                                           \
    {                                                                           \
      const int slot_ = w * 128 + 64 + l;                                       \
      const unsigned short* g_ = h_t + hoff + (size_t)(slot_ >> 3) * NPOS +     \
                                 (size_t)((kt) * 8 + (slot_ & 7)) * 8;          \
      gload_lds16(g_, (unsigned short*)&Bb[buf][0][0] +                         \
                          (size_t)(w * 128 + 64) * 8);                          \
    }                                                                           \
    if (t < 256) {                                                              \
      const unsigned short* g_ = Pub + (size_t)(row0 + (t >> 3)) * (2 * NPOS) + \
                                 NPOS + (size_t)((kt) * 8 + (t & 7)) * 8;       \
      gload_lds16(g_, (unsigned short*)&Ab[buf][0][0] + (size_t)(w * 64) * 8);  \
    }                                                                           \
  } while (0)

  f32x4 acc0 = {0.f, 0.f, 0.f, 0.f}, acc1 = {0.f, 0.f, 0.f, 0.f};
  const int ar = wr * 16 + (l & 15);   // local A row 0..31
  const int lk = l >> 4;
  const int c0 = wc * 32 + (l & 15);
  const int c1 = c0 + 16;
  const int brow = t >> 5;             // beta-write row 0..31
  const int jj = t & 31;               // beta-write k-pair

  STAGE(0, 0);
  __syncthreads();

  int buf = 0;
  for (int kt = 0; kt < 64; ++kt) {
    if (kt < 63) STAGE(buf ^ 1, kt + 1);
    // ---- MFMA: K=64 as 2 k-steps of 32
    {
      const uint4 a0 = Ab[buf][ar][lk ^ (ar & 7)];
      const uint4 a1 = Ab[buf][ar][(4 + lk) ^ (ar & 7)];
      const uint4 b00 = Bb[buf][c0][lk ^ (c0 & 7)];
      const uint4 b01 = Bb[buf][c1][lk ^ (c1 & 7)];
      const uint4 b10 = Bb[buf][c0][(4 + lk) ^ (c0 & 7)];
      const uint4 b11 = Bb[buf][c1][(4 + lk) ^ (c1 & 7)];
      acc0 = __builtin_amdgcn_mfma_f32_16x16x32_bf16(as_s8(a0), as_s8(b00), acc0, 0, 0, 0);
      acc1 = __builtin_amdgcn_mfma_f32_16x16x32_bf16(as_s8(a0), as_s8(b01), acc1, 0, 0, 0);
      acc0 = __builtin_amdgcn_mfma_f32_16x16x32_bf16(as_s8(a1), as_s8(b10), acc0, 0, 0, 0);
      acc1 = __builtin_amdgcn_mfma_f32_16x16x32_bf16(as_s8(a1), as_s8(b11), acc1, 0, 0, 0);
    }
    // ---- beta write: 2 elems/thread from staged A tile
    {
      const float il = linvs[brow];
      const unsigned* arow = reinterpret_cast<const unsigned*>(&Ab[buf][brow][0]);
      const unsigned u = arow[(((jj >> 2) ^ (brow & 7)) << 2) | (jj & 3)];
      float2 v;
      v.x = bf2f((unsigned short)(u & 0xffffu)) * il;
      v.y = bf2f((unsigned short)(u >> 16)) * il;
      *reinterpret_cast<float2*>(beta + (size_t)(b * NPOS + row0 + brow) * NPOS +
                                 (size_t)kt * 64 + jj * 2) = v;
    }
    __syncthreads();
    buf ^= 1;
  }
#undef STAGE

  // epilogue: out = gamma*o/l + x ; C/D: col=lane&15, row=(lane>>4)*4+reg
  const float gam = gamma[0];
#pragma unroll
  for (int r = 0; r < 4; ++r) {
    const int lrr = wr * 16 + (l >> 4) * 4 + r;
    const int orow = row0 + lrr;
    const float sc = gam * linvs[lrr];
    const size_t i0 = ((size_t)b * NPOS + orow) * CDIM + wc * 32 + (l & 15);
    out[i0] = fmaf(sc, acc0[r], x[i0]);
    out[i0 + 16] = fmaf(sc, acc1[r], x[i0 + 16]);
  }
}

extern "C" void kernel_launch(void* const* d_in, const int* in_sizes, int n_in,
                              void* d_out, int out_size, void* d_ws, size_t ws_size,
                              hipStream_t stream) {
  (void)in_sizes; (void)n_in; (void)out_size; (void)ws_size;
  const float* x = (const float*)d_in[0];
  const float* Wf = (const float*)d_in[1];
  const float* Wg = (const float*)d_in[2];
  const float* Wh = (const float*)d_in[3];
  const float* gamma = (const float*)d_in[4];

  float* out = (float*)d_out;                                   // [2*4096*256]
  float* beta = out + (size_t)2 * NPOS * CDIM;                  // [2*4096*4096]

  unsigned short* h_t = (unsigned short*)d_ws;                  // [2*256*4096]
  unsigned short* f_hi = h_t + (size_t)2 * CDIM * NPOS;         // [8192*64] each
  unsigned short* f_lo = f_hi + (size_t)2 * NPOS * FDIM;
  unsigned short* g_hi = f_lo + (size_t)2 * NPOS * FDIM;
  unsigned short* g_lo = g_hi + (size_t)2 * NPOS * FDIM;
  float* lrow = (float*)(g_lo + (size_t)2 * NPOS * FDIM);       // [8192]

  hipLaunchKernelGGL(proj_kernel, dim3(2 * NPOS / 16), dim3(256), 0, stream,
                     x, Wf, Wg, Wh, f_hi, f_lo, g_hi, g_lo, h_t);
  hipLaunchKernelGGL(qk_mfma_kernel, dim3(512), dim3(512), 0, stream,
                     f_hi, f_lo, g_hi, g_lo, beta, lrow);
  hipLaunchKernelGGL(pv_gemm_kernel, dim3(256), dim3(1024), 0, stream,
                     h_t, x, lrow, gamma, beta, out);
}

// Round 11
// 132.977 us; speedup vs baseline: 1.9133x; 1.0275x over previous
//
#include <hip/hip_runtime.h>

#define NPOS 4096
#define CDIM 256
#define FDIM 64

typedef short short8 __attribute__((ext_vector_type(8)));
typedef float f32x4 __attribute__((ext_vector_type(4)));

__device__ __forceinline__ unsigned short f2bf(float v) {
  unsigned u = __float_as_uint(v);
  unsigned r = (u + 0x7fffu + ((u >> 16) & 1u)) >> 16;  // RNE
  return (unsigned short)r;
}
__device__ __forceinline__ float bf2f(unsigned short u) {
  return __uint_as_float((unsigned)u << 16);
}
__device__ __forceinline__ short8 as_s8(uint4 u) {
  return *reinterpret_cast<short8*>(&u);
}
__device__ __forceinline__ void gload_lds16(const void* g, void* l) {
  __builtin_amdgcn_global_load_lds(
      (const __attribute__((address_space(1))) unsigned int*)g,
      (__attribute__((address_space(3))) unsigned int*)l, 16, 0, 0);
}

// ---------------------------------------------------------------------------
// Kernel 1: projections (unchanged from r10).
//   f planes pre-swizzled (chunk c of row r at c^(r&7)); g linear;
//   h_t = (x@Wh)^T bf16, pre-swizzled the same way.
// ---------------------------------------------------------------------------
__global__ __launch_bounds__(256) void proj_kernel(
    const float* __restrict__ x, const float* __restrict__ Wf,
    const float* __restrict__ Wg, const float* __restrict__ Wh,
    unsigned short* __restrict__ f_hi, unsigned short* __restrict__ f_lo,
    unsigned short* __restrict__ g_hi, unsigned short* __restrict__ g_lo,
    unsigned short* __restrict__ h_t) {
  __shared__ float xs[16][CDIM];
  const int row0 = blockIdx.x * 16;
  const int t = threadIdx.x;
  {
    const float4* xv = reinterpret_cast<const float4*>(x + (size_t)row0 * CDIM);
    float4* sv = reinterpret_cast<float4*>(&xs[0][0]);
#pragma unroll
    for (int i = 0; i < 4; ++i) sv[t + 256 * i] = xv[t + 256 * i];
  }
  __syncthreads();
  {
    float acc[16];
#pragma unroll
    for (int r = 0; r < 16; ++r) acc[r] = 0.f;
    for (int k = 0; k < CDIM; k += 4) {
      const float w0 = Wh[(size_t)(k + 0) * CDIM + t];
      const float w1 = Wh[(size_t)(k + 1) * CDIM + t];
      const float w2 = Wh[(size_t)(k + 2) * CDIM + t];
      const float w3 = Wh[(size_t)(k + 3) * CDIM + t];
#pragma unroll
      for (int r = 0; r < 16; ++r) {
        const float4 xv = *reinterpret_cast<const float4*>(&xs[r][k]);
        float a = acc[r];
        a = fmaf(xv.x, w0, a);
        a = fmaf(xv.y, w1, a);
        a = fmaf(xv.z, w2, a);
        a = fmaf(xv.w, w3, a);
        acc[r] = a;
      }
    }
    const int b = row0 >> 12;
    const int lr = row0 & (NPOS - 1);
    unsigned wd[8];
#pragma unroll
    for (int i = 0; i < 8; ++i)
      wd[i] = (unsigned)f2bf(acc[2 * i]) | ((unsigned)f2bf(acc[2 * i + 1]) << 16);
    uint4* base = reinterpret_cast<uint4*>(h_t + ((size_t)(b * CDIM + t)) * NPOS);
    const int m = t & 7;
    const int c0 = lr >> 3;   // even
    base[c0 ^ m] = make_uint4(wd[0], wd[1], wd[2], wd[3]);
    base[(c0 + 1) ^ m] = make_uint4(wd[4], wd[5], wd[6], wd[7]);
  }
  {
    const int col = t & 63;
    const int rb = (t >> 6) * 4;
    const int colq = col >> 3, cwi = col & 7;
    float af[4] = {0.f, 0.f, 0.f, 0.f};
    float ag[4] = {0.f, 0.f, 0.f, 0.f};
    for (int k = 0; k < CDIM; k += 4) {
      const float wf0 = Wf[(size_t)(k + 0) * FDIM + col];
      const float wf1 = Wf[(size_t)(k + 1) * FDIM + col];
      const float wf2 = Wf[(size_t)(k + 2) * FDIM + col];
      const float wf3 = Wf[(size_t)(k + 3) * FDIM + col];
      const float wg0 = Wg[(size_t)(k + 0) * FDIM + col];
      const float wg1 = Wg[(size_t)(k + 1) * FDIM + col];
      const float wg2 = Wg[(size_t)(k + 2) * FDIM + col];
      const float wg3 = Wg[(size_t)(k + 3) * FDIM + col];
#pragma unroll
      for (int r = 0; r < 4; ++r) {
        const float4 xv = *reinterpret_cast<const float4*>(&xs[rb + r][k]);
        float a = af[r], bb = ag[r];
        a = fmaf(xv.x, wf0, a); a = fmaf(xv.y, wf1, a);
        a = fmaf(xv.z, wf2, a); a = fmaf(xv.w, wf3, a);
        bb = fmaf(xv.x, wg0, bb); bb = fmaf(xv.y, wg1, bb);
        bb = fmaf(xv.z, wg2, bb); bb = fmaf(xv.w, wg3, bb);
        af[r] = a; ag[r] = bb;
      }
    }
#pragma unroll
    for (int r = 0; r < 4; ++r) {
      const int row = row0 + rb + r;
      const int ph = ((colq ^ (row & 7)) << 3) | cwi;
      const size_t of = (size_t)row * FDIM + ph;
      const size_t og = (size_t)row * FDIM + col;
      const unsigned short fh = f2bf(af[r]);
      const unsigned short gh = f2bf(ag[r]);
      f_hi[of] = fh;
      f_lo[of] = f2bf(af[r] - bf2f(fh));
      g_hi[og] = gh;
      g_lo[og] = f2bf(ag[r] - bf2f(gh));
    }
  }
}

// ---------------------------------------------------------------------------
// Kernel 2 (FUSED qk+pv): block = 32 beta-rows, 1024 threads / 16 waves.
// Phase A (r10 qk structure, 16 waves = 2 row-halves x 8 col-strips):
//   s = g f^T (bf16x3, swapped operands), P = bf16(exp(s)) -> 2nd half of
//   beta rows (swizzled), row sums kept in LDS (no global lrow).
// Phase B (r10 pv verbatim): A(P)/B(h_t) DMA-staged GEMM; beta = P/l fp32
//   written in-stream; out = gamma*o/l + x. P re-read is same-XCD L2-hot.
// Barriers: s_waitcnt vmcnt(1) (exclude own newest store from the drain;
// gloads pinned above the body via sched_barrier) + raw s_barrier.
// ---------------------------------------------------------------------------
__global__ __launch_bounds__(1024, 4) void attn_fused_kernel(
    const unsigned short* __restrict__ f_hi, const unsigned short* __restrict__ f_lo,
    const unsigned short* __restrict__ g_hi, const unsigned short* __restrict__ g_lo,
    const unsigned short* __restrict__ h_t, const float* __restrict__ x,
    const float* __restrict__ gamma, float* __restrict__ beta,
    float* __restrict__ out) {
  __shared__ __align__(16) char shraw[73728];   // A: Fh(32K)+Fl(32K); B: Ab(8K)+Bb(64K)
  __shared__ float partl[16][16];
  __shared__ float linvs[32];
  uint4 (*Fh)[128][8] = reinterpret_cast<uint4(*)[128][8]>(shraw);
  uint4 (*Fl)[128][8] = reinterpret_cast<uint4(*)[128][8]>(shraw + 32768);
  uint4 (*Ab)[32][8] = reinterpret_cast<uint4(*)[32][8]>(shraw);
  uint4 (*Bb)[256][8] = reinterpret_cast<uint4(*)[256][8]>(shraw + 8192);

  const int wg = blockIdx.x;
  const int wgid = (wg & 7) * 32 + (wg >> 3);   // bijective XCD chunking (256 wgs)
  const int b = wgid >> 7;
  const int row0 = (wgid & 127) * 32;
  const int t = threadIdx.x;
  const int w = t >> 6;
  const int l = t & 63;
  const int lr = l & 15;
  const int lk = l >> 4;

  // ============================ Phase A ============================
  const int wr = w >> 3;     // row half (0/1)
  const int wq = w & 7;      // col strip
  const int arow = row0 + wr * 16 + lr;   // this lane's beta row
  short8 gh[2], gl[2];
  {
    const unsigned short* gH = g_hi + ((size_t)(b * NPOS + arow)) * FDIM + lk * 8;
    const unsigned short* gL = g_lo + ((size_t)(b * NPOS + arow)) * FDIM + lk * 8;
#pragma unroll
    for (int ks = 0; ks < 2; ++ks) {
      gh[ks] = *reinterpret_cast<const short8*>(gH + ks * 32);
      gl[ks] = *reinterpret_cast<const short8*>(gL + ks * 32);
    }
  }
  const unsigned short* fbh = f_hi + (size_t)b * NPOS * FDIM;
  const unsigned short* fbl = f_lo + (size_t)b * NPOS * FDIM;
  unsigned short* Pb = (unsigned short*)(beta + (size_t)b * NPOS * NPOS);
  unsigned short* prow = Pb + (size_t)arow * (2 * NPOS) + NPOS;
  const int rsw = lr & 7;
  float lsum = 0.f;
  const int srow_ = t >> 3, sch_ = t & 7;   // staging: slot t of 1024

#define STAGEA(buf, tile)                                                      \
  do {                                                                         \
    const int tr_ = (tile) * 128 + srow_;                                      \
    gload_lds16(fbh + (size_t)tr_ * FDIM + sch_ * 8,                           \
                (char*)&Fh[buf][0][0] + (size_t)t * 16);                       \
    gload_lds16(fbl + (size_t)tr_ * FDIM + sch_ * 8,                           \
                (char*)&Fl[buf][0][0] + (size_t)t * 16);                       \
  } while (0)

  STAGEA(0, 0);
  asm volatile("s_waitcnt vmcnt(0) lgkmcnt(0)\ns_barrier" ::: "memory");

  const int rrA = wq * 16 + lr;
  const int fsw = rrA & 7;
  int buf = 0;
  for (int tile = 0; tile < 32; ++tile) {
    if (tile < 31) STAGEA(buf ^ 1, tile + 1);
    __builtin_amdgcn_sched_barrier(0);   // pin gloads at top (vmcnt count safety)
    const uint4 h0 = Fh[buf][rrA][lk ^ fsw];
    const uint4 h1 = Fh[buf][rrA][(lk + 4) ^ fsw];
    const uint4 q0 = Fl[buf][rrA][lk ^ fsw];
    const uint4 q1 = Fl[buf][rrA][(lk + 4) ^ fsw];
    f32x4 acca = {0.f, 0.f, 0.f, 0.f};
    f32x4 accb = {0.f, 0.f, 0.f, 0.f};
    acca = __builtin_amdgcn_mfma_f32_16x16x32_bf16(as_s8(h0), gh[0], acca, 0, 0, 0);
    accb = __builtin_amdgcn_mfma_f32_16x16x32_bf16(as_s8(h0), gl[0], accb, 0, 0, 0);
    acca = __builtin_amdgcn_mfma_f32_16x16x32_bf16(as_s8(q0), gh[0], acca, 0, 0, 0);
    accb = __builtin_amdgcn_mfma_f32_16x16x32_bf16(as_s8(h1), gh[1], accb, 0, 0, 0);
    acca = __builtin_amdgcn_mfma_f32_16x16x32_bf16(as_s8(q1), gh[1], acca, 0, 0, 0);
    accb = __builtin_amdgcn_mfma_f32_16x16x32_bf16(as_s8(h1), gl[1], accb, 0, 0, 0);
    const f32x4 acc = acca + accb;
    const int cq = tile * 128 + wq * 16 + lk * 4;   // 4 consecutive beta-cols
    const float e0 = __expf(acc[0]);
    const float e1 = __expf(acc[1]);
    const float e2 = __expf(acc[2]);
    const float e3 = __expf(acc[3]);
    lsum += (e0 + e1) + (e2 + e3);
    uint2 pk;
    pk.x = (unsigned)f2bf(e0) | ((unsigned)f2bf(e1) << 16);
    pk.y = (unsigned)f2bf(e2) | ((unsigned)f2bf(e3) << 16);
    const int sidx = (((cq >> 3) ^ rsw) << 3) | (cq & 7);
    *reinterpret_cast<uint2*>(prow + sidx) = pk;
    // counted barrier: newest outstanding = the P store; gloads(tile+1) drained
    asm volatile("s_waitcnt vmcnt(1) lgkmcnt(0)\ns_barrier" ::: "memory");
    buf ^= 1;
  }
#undef STAGEA

  // row sums -> linvs (LDS only; no global round-trip)
  lsum += __shfl_xor(lsum, 16);
  lsum += __shfl_xor(lsum, 32);
  if (l < 16) partl[w][l] = lsum;
  __syncthreads();
  if (t < 32) {
    const int half = t >> 4;
    float s = 0.f;
#pragma unroll
    for (int q = 0; q < 8; ++q) s += partl[half * 8 + q][t & 15];
    linvs[t] = __frcp_rn(s);
  }
  // drain ALL P stores before phase B's DMA re-reads them; publish linvs
  asm volatile("s_waitcnt vmcnt(0) lgkmcnt(0)\ns_barrier" ::: "memory");

  // ============================ Phase B ============================
  const size_t hoff = (size_t)b * CDIM * NPOS;
  const unsigned short* Pub = (const unsigned short*)(beta + (size_t)b * NPOS * NPOS);

#define STAGEB(buf, kt)                                                         \
  do {                                                                          \
    {                                                                           \
      const int slot_ = w * 128 + l;                                            \
      const unsigned short* g_ = h_t + hoff + (size_t)(slot_ >> 3) * NPOS +     \
                                 (size_t)((kt) * 8 + (slot_ & 7)) * 8;          \
      gload_lds16(g_, (unsigned short*)&Bb[buf][0][0] + (size_t)(w * 128) * 8); \
    }                                                                           \
    {                                                                           \
      const int slot_ = w * 128 + 64 + l;                                       \
      const unsigned short* g_ = h_t + hoff + (size_t)(slot_ >> 3) * NPOS +     \
                                 (size_t)((kt) * 8 + (slot_ & 7)) * 8;          \
      gload_lds16(g_, (unsigned short*)&Bb[buf][0][0] +                         \
                          (size_t)(w * 128 + 64) * 8);                          \
    }                                                                           \
    if (t < 256) {                                                              \
      const unsigned short* g_ = Pub + (size_t)(row0 + (t >> 3)) * (2 * NPOS) + \
                                 NPOS + (size_t)((kt) * 8 + (t & 7)) * 8;       \
      gload_lds16(g_, (unsigned short*)&Ab[buf][0][0] + (size_t)(w * 64) * 8);  \
    }                                                                           \
  } while (0)

  f32x4 acc0 = {0.f, 0.f, 0.f, 0.f}, acc1 = {0.f, 0.f, 0.f, 0.f};
  const int wrB = w & 1;
  const int wcB = w >> 1;
  const int arB = wrB * 16 + lr;       // local A row 0..31
  const int c0 = wcB * 32 + lr;
  const int c1 = c0 + 16;
  const int brow = t >> 5;             // beta-write row 0..31
  const int jj = t & 31;               // beta-write k-pair

  STAGEB(0, 0);
  asm volatile("s_waitcnt vmcnt(0) lgkmcnt(0)\ns_barrier" ::: "memory");

  buf = 0;
  for (int kt = 0; kt < 64; ++kt) {
    if (kt < 63) STAGEB(buf ^ 1, kt + 1);
    __builtin_amdgcn_sched_barrier(0);   // pin gloads at top
    // ---- MFMA: K=64 as 2 k-steps of 32
    {
      const uint4 a0 = Ab[buf][arB][lk ^ (arB & 7)];
      const uint4 a1 = Ab[buf][arB][(4 + lk) ^ (arB & 7)];
      const uint4 b00 = Bb[buf][c0][lk ^ (c0 & 7)];
      const uint4 b01 = Bb[buf][c1][lk ^ (c1 & 7)];
      const uint4 b10 = Bb[buf][c0][(4 + lk) ^ (c0 & 7)];
      const uint4 b11 = Bb[buf][c1][(4 + lk) ^ (c1 & 7)];
      acc0 = __builtin_amdgcn_mfma_f32_16x16x32_bf16(as_s8(a0), as_s8(b00), acc0, 0, 0, 0);
      acc1 = __builtin_amdgcn_mfma_f32_16x16x32_bf16(as_s8(a0), as_s8(b01), acc1, 0, 0, 0);
      acc0 = __builtin_amdgcn_mfma_f32_16x16x32_bf16(as_s8(a1), as_s8(b10), acc0, 0, 0, 0);
      acc1 = __builtin_amdgcn_mfma_f32_16x16x32_bf16(as_s8(a1), as_s8(b11), acc1, 0, 0, 0);
    }
    // ---- beta write: 2 elems/thread from staged A tile
    {
      const float il = linvs[brow];
      const unsigned* arow_ = reinterpret_cast<const unsigned*>(&Ab[buf][brow][0]);
      const unsigned u = arow_[(((jj >> 2) ^ (brow & 7)) << 2) | (jj & 3)];
      float2 v;
      v.x = bf2f((unsigned short)(u & 0xffffu)) * il;
      v.y = bf2f((unsigned short)(u >> 16)) * il;
      *reinterpret_cast<float2*>(beta + (size_t)(b * NPOS + row0 + brow) * NPOS +
                                 (size_t)kt * 64 + jj * 2) = v;
    }
    // counted barrier: newest outstanding = the beta store
    asm volatile("s_waitcnt vmcnt(1) lgkmcnt(0)\ns_barrier" ::: "memory");
    buf ^= 1;
  }
#undef STAGEB

  // epilogue: out = gamma*o/l + x ; C/D: col=lane&15, row=(lane>>4)*4+reg
  const float gam = gamma[0];
#pragma unroll
  for (int r = 0; r < 4; ++r) {
    const int lrr = wrB * 16 + lk * 4 + r;
    const int orow = row0 + lrr;
    const float sc = gam * linvs[lrr];
    const size_t i0 = ((size_t)b * NPOS + orow) * CDIM + wcB * 32 + lr;
    out[i0] = fmaf(sc, acc0[r], x[i0]);
    out[i0 + 16] = fmaf(sc, acc1[r], x[i0 + 16]);
  }
}

extern "C" void kernel_launch(void* const* d_in, const int* in_sizes, int n_in,
                              void* d_out, int out_size, void* d_ws, size_t ws_size,
                              hipStream_t stream) {
  (void)in_sizes; (void)n_in; (void)out_size; (void)ws_size;
  const float* x = (const float*)d_in[0];
  const float* Wf = (const float*)d_in[1];
  const float* Wg = (const float*)d_in[2];
  const float* Wh = (const float*)d_in[3];
  const float* gamma = (const float*)d_in[4];

  float* out = (float*)d_out;                                   // [2*4096*256]
  float* beta = out + (size_t)2 * NPOS * CDIM;                  // [2*4096*4096]

  unsigned short* h_t = (unsigned short*)d_ws;                  // [2*256*4096]
  unsigned short* f_hi = h_t + (size_t)2 * CDIM * NPOS;         // [8192*64] each
  unsigned short* f_lo = f_hi + (size_t)2 * NPOS * FDIM;
  unsigned short* g_hi = f_lo + (size_t)2 * NPOS * FDIM;
  unsigned short* g_lo = g_hi + (size_t)2 * NPOS * FDIM;

  hipLaunchKernelGGL(proj_kernel, dim3(2 * NPOS / 16), dim3(256), 0, stream,
                     x, Wf, Wg, Wh, f_hi, f_lo, g_hi, g_lo, h_t);
  hipLaunchKernelGGL(attn_fused_kernel, dim3(256), dim3(1024), 0, stream,
                     f_hi, f_lo, g_hi, g_lo, h_t, x, gamma, beta, out);
}